// Round 2
// baseline (220.801 us; speedup 1.0000x reference)
//
#include <hip/hip_runtime.h>
#include <math.h>

#define E_N 50
#define D_N 100
#define H_N 100
#define GPB 4            // graphs per block
#define NTHR 256
#define SSP (E_N + 2)    // padded row for 50-wide LDS arrays

// workspace layout (f32 always): At[10000], c[100]
//   At[dp*100 + d] = sum_h Wk[d,h] * Wq[dp,h]   (A transposed for coalesced reads)
//   c[d]           = sum_h Wk[d,h] * bq[h]
#define WS_AT 0
#define WS_C  (D_N * D_N)
#define WS_FLOATS (D_N * D_N + D_N)

__device__ __forceinline__ float bf2f(unsigned int s16) {
    return __uint_as_float(s16 << 16);
}

__device__ __forceinline__ unsigned short f2bf(float f) {
    unsigned int u = __float_as_uint(f);
    unsigned int r = (u + 0x7FFFu + ((u >> 16) & 1u)) >> 16;  // round-nearest-even
    return (unsigned short)r;
}

template <bool F32>
__device__ __forceinline__ float ldx(const void* p, int i) {
    if (F32) return reinterpret_cast<const float*>(p)[i];
    return bf2f(reinterpret_cast<const unsigned short*>(p)[i]);
}

template <bool F32>
__device__ __forceinline__ float4 ld4(const void* p, long long i4) {
    if (F32) return reinterpret_cast<const float4*>(p)[i4];
    uint2 v = reinterpret_cast<const uint2*>(p)[i4];
    float4 f;
    f.x = bf2f(v.x & 0xFFFFu);
    f.y = bf2f(v.x >> 16);
    f.z = bf2f(v.y & 0xFFFFu);
    f.w = bf2f(v.y >> 16);
    return f;
}

// dtype detector: even halfwords of emb decode sane iff data is bf16
// (f32 little-endian even halfwords are low-mantissa bits -> garbage exponents)
__device__ __forceinline__ int sniff_f32(const void* emb, int tid, int* slot) {
    if (tid < 64) {
        unsigned short hw = reinterpret_cast<const unsigned short*>(emb)[tid * 2];
        float v = bf2f(hw);
        float a = fabsf(v);
        int sane = (v == 0.f) || (a >= 1e-4f && a <= 8.0f);
        unsigned long long ball = __ballot(sane);
        if (tid == 0) *slot = (__popcll(ball) < 32) ? 1 : 0;
    }
    __syncthreads();
    return *slot;
}

// ---------------- kernel 1: precompute A = Wk Wq^T (transposed) and c = Wk bq ----------------
template <bool F32>
__device__ __forceinline__ void precomp_core(
    int dp, int tid, const void* __restrict__ Wq, const void* __restrict__ bq,
    const void* __restrict__ Wk, float* __restrict__ ws, float* wq_s, float* bq_s)
{
    if (tid < H_N) wq_s[tid] = ldx<F32>(Wq, dp * H_N + tid);        // Wq[dp,:] coalesced
    if (dp == 0 && tid < H_N) bq_s[tid] = ldx<F32>(bq, tid);
    __syncthreads();
    if (tid < D_N) {
        float a0 = 0.f, a1 = 0.f, a2 = 0.f, a3 = 0.f;
        #pragma unroll
        for (int h4 = 0; h4 < H_N / 4; ++h4) {
            float4 w = ld4<F32>(Wk, (long long)tid * (H_N / 4) + h4);  // Wk[tid,:] row
            a0 = fmaf(w.x, wq_s[h4 * 4 + 0], a0);
            a1 = fmaf(w.y, wq_s[h4 * 4 + 1], a1);
            a2 = fmaf(w.z, wq_s[h4 * 4 + 2], a2);
            a3 = fmaf(w.w, wq_s[h4 * 4 + 3], a3);
        }
        ws[WS_AT + dp * D_N + tid] = (a0 + a1) + (a2 + a3);
        if (dp == 0) {
            float c0 = 0.f, c1 = 0.f, c2 = 0.f, c3 = 0.f;
            #pragma unroll
            for (int h4 = 0; h4 < H_N / 4; ++h4) {
                float4 w = ld4<F32>(Wk, (long long)tid * (H_N / 4) + h4);
                c0 = fmaf(w.x, bq_s[h4 * 4 + 0], c0);
                c1 = fmaf(w.y, bq_s[h4 * 4 + 1], c1);
                c2 = fmaf(w.z, bq_s[h4 * 4 + 2], c2);
                c3 = fmaf(w.w, bq_s[h4 * 4 + 3], c3);
            }
            ws[WS_C + tid] = (c0 + c1) + (c2 + c3);
        }
    }
}

__global__ __launch_bounds__(128)
void precomp_kernel(const void* __restrict__ Wq, const void* __restrict__ bq,
                    const void* __restrict__ Wk, const void* __restrict__ emb,
                    float* __restrict__ ws)
{
    __shared__ float wq_s[H_N];
    __shared__ float bq_s[H_N];
    __shared__ int is_f32_s;
    int f32 = sniff_f32(emb, threadIdx.x, &is_f32_s);
    if (f32) precomp_core<true >(blockIdx.x, threadIdx.x, Wq, bq, Wk, ws, wq_s, bq_s);
    else     precomp_core<false>(blockIdx.x, threadIdx.x, Wq, bq, Wk, ws, wq_s, bq_s);
}

// ---------------- kernel 2: 4 ego-graphs per block ----------------
// per graph g:  w = A x0 + c;  s_j = 0.1 * x_j.w (masked softmax -> p_j)
//               y = sum_j p_j x_j;  out = bs + bv*[any edge] + y.Wv + x0.Ws
template <bool F32>
__device__ __forceinline__ void graph_core(
    int g0, int G, int tid,
    const int* __restrict__ nbr, const int* __restrict__ adj,
    const void* __restrict__ emb,
    const void* __restrict__ Wv, const void* __restrict__ bv,
    const void* __restrict__ Ws, const void* __restrict__ bs,
    const float* __restrict__ ws, void* __restrict__ out,
    float* x0s, float* wls, float* ss, float* es, float* ps,
    float* ys, float* skc, int* ids_s, float* denf)
{
    // ---- phase A: ids + mask + x0 rows ----
    int q_ = 0, j_ = 0, myid = 0, mymsk = 0;
    if (tid < GPB * E_N) {
        q_ = tid / E_N; j_ = tid - q_ * E_N;
        int gq = g0 + q_; if (gq >= G) gq = G - 1;
        myid = nbr[gq * E_N + j_];
        ids_s[q_ * SSP + j_] = myid;
        mymsk = adj[(size_t)gq * (E_N * E_N) + j_ * E_N];   // mask[i=0, j] = adj[j, 0]
    }
    if (tid < GPB * (D_N / 4)) {
        int qq = tid / (D_N / 4), d4 = tid - qq * (D_N / 4);
        int gq = g0 + qq; if (gq >= G) gq = G - 1;
        int id0 = nbr[gq * E_N];
        float4 v = ld4<F32>(emb, (long long)id0 * (D_N / 4) + d4);
        reinterpret_cast<float4*>(x0s + qq * D_N)[d4] = v;
    }
    __syncthreads();

    // ---- phase B: waves 0-1: w_q = A x0_q + c (A streamed ONCE for 4 graphs)
    //               waves 2-3: skip_q = x0_q . Ws   (Ws streamed once for 4 graphs)
    if (tid < D_N) {
        float cv = ws[WS_C + tid];
        float a0 = cv, a1 = cv, a2 = cv, a3 = cv;
        #pragma unroll 4
        for (int dp = 0; dp < D_N; ++dp) {
            float a = ws[WS_AT + dp * D_N + tid];           // coalesced over lanes
            a0 = fmaf(a, x0s[0 * D_N + dp], a0);            // LDS broadcasts
            a1 = fmaf(a, x0s[1 * D_N + dp], a1);
            a2 = fmaf(a, x0s[2 * D_N + dp], a2);
            a3 = fmaf(a, x0s[3 * D_N + dp], a3);
        }
        wls[0 * D_N + tid] = a0; wls[1 * D_N + tid] = a1;
        wls[2 * D_N + tid] = a2; wls[3 * D_N + tid] = a3;
    } else if (tid >= 128 && tid < 128 + H_N) {
        int h = tid - 128;
        float s0 = 0.f, s1 = 0.f, s2 = 0.f, s3 = 0.f;
        #pragma unroll 4
        for (int d = 0; d < D_N; ++d) {
            float w = ldx<F32>(Ws, d * H_N + h);            // coalesced over lanes
            s0 = fmaf(w, x0s[0 * D_N + d], s0);
            s1 = fmaf(w, x0s[1 * D_N + d], s1);
            s2 = fmaf(w, x0s[2 * D_N + d], s2);
            s3 = fmaf(w, x0s[3 * D_N + d], s3);
        }
        skc[0 * H_N + h] = s0; skc[1 * H_N + h] = s1;
        skc[2 * H_N + h] = s2; skc[3 * H_N + h] = s3;
    }
    __syncthreads();

    // ---- phase C: scores (row-per-thread gather) + masked softmax ----
    float s_reg = 0.f, e_reg = 0.f;
    if (tid < GPB * E_N) {
        const float* wv = wls + q_ * D_N;
        float a0 = 0.f, a1 = 0.f, a2 = 0.f, a3 = 0.f;
        #pragma unroll
        for (int d4 = 0; d4 < D_N / 4; ++d4) {
            float4 xv = ld4<F32>(emb, (long long)myid * (D_N / 4) + d4);
            a0 = fmaf(xv.x, wv[4 * d4 + 0], a0);
            a1 = fmaf(xv.y, wv[4 * d4 + 1], a1);
            a2 = fmaf(xv.z, wv[4 * d4 + 2], a2);
            a3 = fmaf(xv.w, wv[4 * d4 + 3], a3);
        }
        s_reg = ((a0 + a1) + (a2 + a3)) * 0.1f;             // 1/sqrt(H)
        ss[q_ * SSP + j_] = mymsk ? s_reg : -3.0e38f;
    }
    __syncthreads();
    if (tid < GPB * E_N) {
        float m = -3.0e38f;
        #pragma unroll
        for (int j = 0; j < E_N; ++j) m = fmaxf(m, ss[q_ * SSP + j]);  // LDS broadcast
        e_reg = mymsk ? __expf(s_reg - m) : 0.f;
        es[q_ * SSP + j_] = e_reg;
    }
    __syncthreads();
    if (tid < GPB * E_N) {
        float den = 0.f;
        #pragma unroll
        for (int j = 0; j < E_N; ++j) den += es[q_ * SSP + j];
        float inv = den > 0.f ? 1.f / den : 0.f;
        ps[q_ * SSP + j_] = e_reg * inv;                    // pre-normalized
        if (j_ == 0) denf[q_] = den;
    }
    __syncthreads();

    // ---- phase D: y_q[d] = sum_j p_j x_j[d]  (re-read rows, L2-hot) ----
    #pragma unroll
    for (int rep = 0; rep < 2; ++rep) {
        int idx = tid + NTHR * rep;
        if (idx < GPB * D_N) {
            int q = idx / D_N, d = idx - q * D_N;
            float acc = 0.f;
            #pragma unroll 10
            for (int j = 0; j < E_N; ++j) {
                float p = ps[q * SSP + j];                  // LDS broadcast
                if (p > 0.f) {
                    int id = ids_s[q * SSP + j];
                    acc = fmaf(p, ldx<F32>(emb, id * D_N + d), acc);  // coalesced over lanes
                }
            }
            ys[q * D_N + d] = acc;
        }
    }
    __syncthreads();

    // ---- phase E: out_q[h] = bs + bv*[den>0] + y_q.Wv[:,h] + skip_q[h] ----
    if (tid < H_N) {
        float b   = ldx<F32>(bs, tid);
        float bvv = ldx<F32>(bv, tid);
        float a0 = b + (denf[0] > 0.f ? bvv : 0.f) + skc[0 * H_N + tid];
        float a1 = b + (denf[1] > 0.f ? bvv : 0.f) + skc[1 * H_N + tid];
        float a2 = b + (denf[2] > 0.f ? bvv : 0.f) + skc[2 * H_N + tid];
        float a3 = b + (denf[3] > 0.f ? bvv : 0.f) + skc[3 * H_N + tid];
        #pragma unroll 4
        for (int d = 0; d < D_N; ++d) {
            float w = ldx<F32>(Wv, d * H_N + tid);          // streamed once for 4 graphs
            a0 = fmaf(w, ys[0 * D_N + d], a0);
            a1 = fmaf(w, ys[1 * D_N + d], a1);
            a2 = fmaf(w, ys[2 * D_N + d], a2);
            a3 = fmaf(w, ys[3 * D_N + d], a3);
        }
        float accs[GPB] = {a0, a1, a2, a3};
        #pragma unroll
        for (int q = 0; q < GPB; ++q) {
            int gq = g0 + q;
            if (gq < G) {
                size_t o = (size_t)gq * H_N + tid;
                if (F32) reinterpret_cast<float*>(out)[o] = accs[q];
                else     reinterpret_cast<unsigned short*>(out)[o] = f2bf(accs[q]);
            }
        }
    }
}

__global__ __launch_bounds__(NTHR, 4)
void graph_enc_kernel(const int* __restrict__ nbr,
                      const int* __restrict__ adj,
                      const void* __restrict__ emb,
                      const void* __restrict__ Wv, const void* __restrict__ bv,
                      const void* __restrict__ Ws, const void* __restrict__ bs,
                      const float* __restrict__ ws, void* __restrict__ out, int G)
{
    const int g0 = blockIdx.x * GPB;
    const int tid = threadIdx.x;

    __shared__ __align__(16) float x0s[GPB * D_N];
    __shared__ __align__(16) float wls[GPB * D_N];
    __shared__ __align__(16) float ss [GPB * SSP];
    __shared__ __align__(16) float es [GPB * SSP];
    __shared__ __align__(16) float ps [GPB * SSP];
    __shared__ __align__(16) float ys [GPB * D_N];
    __shared__ __align__(16) float skc[GPB * H_N];
    __shared__ __align__(16) int   ids_s[GPB * SSP];
    __shared__ float denf[GPB];
    __shared__ int is_f32_s;

    int f32 = sniff_f32(emb, tid, &is_f32_s);
    if (f32)
        graph_core<true >(g0, G, tid, nbr, adj, emb, Wv, bv, Ws, bs, ws, out,
                          x0s, wls, ss, es, ps, ys, skc, ids_s, denf);
    else
        graph_core<false>(g0, G, tid, nbr, adj, emb, Wv, bv, Ws, bs, ws, out,
                          x0s, wls, ss, es, ps, ys, skc, ids_s, denf);
}

extern "C" void kernel_launch(void* const* d_in, const int* in_sizes, int n_in,
                              void* d_out, int out_size, void* d_ws, size_t ws_size,
                              hipStream_t stream) {
    const int* nbr = (const int*)d_in[0];
    const int* adj = (const int*)d_in[1];
    const void* emb = d_in[2];
    const void* Wq  = d_in[3];
    const void* bq  = d_in[4];
    const void* Wk  = d_in[5];   // d_in[6] = bk cancels inside softmax — unused
    const void* Wv  = d_in[7];
    const void* bv  = d_in[8];
    const void* Ws  = d_in[9];
    const void* bs  = d_in[10];

    float* ws = (float*)d_ws;    // needs WS_FLOATS*4 = 40,400 B of workspace
    const int G = in_sizes[0] / E_N;  // B*L = 3200

    precomp_kernel<<<D_N, 128, 0, stream>>>(Wq, bq, Wk, emb, ws);
    graph_enc_kernel<<<(G + GPB - 1) / GPB, NTHR, 0, stream>>>(
        nbr, adj, emb, Wv, bv, Ws, bs, ws, d_out, G);
}

// Round 3
// 189.892 us; speedup vs baseline: 1.1628x; 1.1628x over previous
//
#include <hip/hip_runtime.h>
#include <math.h>

#define E_N 50
#define D_N 100
#define H_N 100
#define XSTR 51          // odd LDS row stride: conflict-free for both access patterns
#define GT 8             // graphs per block in dense kernels
#define NTHR 256
#define GATHER_IT 5      // ceil(50*25 / 256)

__device__ __forceinline__ float bf2f(unsigned int s16) {
    return __uint_as_float(s16 << 16);
}

__device__ __forceinline__ unsigned short f2bf(float f) {
    unsigned int u = __float_as_uint(f);
    unsigned int r = (u + 0x7FFFu + ((u >> 16) & 1u)) >> 16;  // round-nearest-even
    return (unsigned short)r;
}

template <bool F32>
__device__ __forceinline__ float ldx(const void* p, int i) {
    if (F32) return reinterpret_cast<const float*>(p)[i];
    return bf2f(reinterpret_cast<const unsigned short*>(p)[i]);
}

template <bool F32>
__device__ __forceinline__ float4 ld4(const void* p, long long i4) {
    if (F32) return reinterpret_cast<const float4*>(p)[i4];
    uint2 v = reinterpret_cast<const uint2*>(p)[i4];
    float4 f;
    f.x = bf2f(v.x & 0xFFFFu);
    f.y = bf2f(v.x >> 16);
    f.z = bf2f(v.y & 0xFFFFu);
    f.w = bf2f(v.y >> 16);
    return f;
}

// dtype detector: even halfwords of emb decode sane iff data is bf16
__device__ __forceinline__ int sniff_f32(const void* emb, int tid, int* slot) {
    if (tid < 64) {
        unsigned short hw = reinterpret_cast<const unsigned short*>(emb)[tid * 2];
        float v = bf2f(hw);
        float a = fabsf(v);
        int sane = (v == 0.f) || (a >= 1e-4f && a <= 8.0f);
        unsigned long long ball = __ballot(sane);
        if (tid == 0) *slot = (__popcll(ball) < 32) ? 1 : 0;
    }
    __syncthreads();
    return *slot;
}

// ============ K0: At[dp*100+d] = sum_h Wk[d,h]Wq[dp,h]; c[d] = sum_h Wk[d,h]bq[h] ============
template <bool F32>
__device__ __forceinline__ void precomp_core(
    int dp, int tid, const void* __restrict__ Wq, const void* __restrict__ bq,
    const void* __restrict__ Wk, float* __restrict__ At, float* __restrict__ c,
    float* wq_s, float* bq_s)
{
    if (tid < H_N) wq_s[tid] = ldx<F32>(Wq, dp * H_N + tid);
    if (dp == 0 && tid < H_N) bq_s[tid] = ldx<F32>(bq, tid);
    __syncthreads();
    if (tid < D_N) {
        float a0 = 0.f, a1 = 0.f, a2 = 0.f, a3 = 0.f;
        #pragma unroll
        for (int h4 = 0; h4 < H_N / 4; ++h4) {
            float4 w = ld4<F32>(Wk, (long long)tid * (H_N / 4) + h4);
            a0 = fmaf(w.x, wq_s[h4 * 4 + 0], a0);
            a1 = fmaf(w.y, wq_s[h4 * 4 + 1], a1);
            a2 = fmaf(w.z, wq_s[h4 * 4 + 2], a2);
            a3 = fmaf(w.w, wq_s[h4 * 4 + 3], a3);
        }
        At[dp * D_N + tid] = (a0 + a1) + (a2 + a3);
        if (dp == 0) {
            float c0 = 0.f, c1 = 0.f, c2 = 0.f, c3 = 0.f;
            #pragma unroll
            for (int h4 = 0; h4 < H_N / 4; ++h4) {
                float4 w = ld4<F32>(Wk, (long long)tid * (H_N / 4) + h4);
                c0 = fmaf(w.x, bq_s[h4 * 4 + 0], c0);
                c1 = fmaf(w.y, bq_s[h4 * 4 + 1], c1);
                c2 = fmaf(w.z, bq_s[h4 * 4 + 2], c2);
                c3 = fmaf(w.w, bq_s[h4 * 4 + 3], c3);
            }
            c[tid] = (c0 + c1) + (c2 + c3);
        }
    }
}

__global__ __launch_bounds__(128)
void precomp_kernel(const void* __restrict__ Wq, const void* __restrict__ bq,
                    const void* __restrict__ Wk, const void* __restrict__ emb,
                    float* __restrict__ At, float* __restrict__ c)
{
    __shared__ float wq_s[H_N];
    __shared__ float bq_s[H_N];
    __shared__ int is_f32_s;
    int f32 = sniff_f32(emb, threadIdx.x, &is_f32_s);
    if (f32) precomp_core<true >(blockIdx.x, threadIdx.x, Wq, bq, Wk, At, c, wq_s, bq_s);
    else     precomp_core<false>(blockIdx.x, threadIdx.x, Wq, bq, Wk, At, c, wq_s, bq_s);
}

// ============ K1 (dense): wl_g = A x0_g + c ; skip_g = x0_g . Ws  (GT graphs/block) ============
template <bool F32>
__device__ __forceinline__ void ka_core(
    int g0, int G, int tid,
    const int* __restrict__ nbr, const void* __restrict__ emb,
    const float* __restrict__ At, const float* __restrict__ c,
    const void* __restrict__ Ws,
    float* __restrict__ wl, float* __restrict__ skip, float* x0s)
{
    if (tid < GT * (D_N / 4)) {
        int q = tid / (D_N / 4), d4 = tid - q * (D_N / 4);
        int gq = g0 + q; if (gq >= G) gq = G - 1;
        int id0 = nbr[gq * E_N];
        float4 v = ld4<F32>(emb, (long long)id0 * (D_N / 4) + d4);
        reinterpret_cast<float4*>(x0s + q * D_N)[d4] = v;
    }
    __syncthreads();

    if (tid < D_N) {                    // waves 0-1: wl (At streamed coalesced once for GT graphs)
        int d = tid;
        float cv = c[d];
        float acc[GT];
        #pragma unroll
        for (int q = 0; q < GT; ++q) acc[q] = cv;
        #pragma unroll 4
        for (int dp = 0; dp < D_N; ++dp) {
            float a = At[dp * D_N + d];
            #pragma unroll
            for (int q = 0; q < GT; ++q)
                acc[q] = fmaf(a, x0s[q * D_N + dp], acc[q]);
        }
        #pragma unroll
        for (int q = 0; q < GT; ++q) {
            int gq = g0 + q;
            if (gq < G) wl[(size_t)gq * D_N + d] = acc[q];
        }
    } else if (tid >= 128 && tid < 128 + H_N) {       // waves 2-3: skip (Ws streamed once)
        int h = tid - 128;
        float acc[GT];
        #pragma unroll
        for (int q = 0; q < GT; ++q) acc[q] = 0.f;
        #pragma unroll 4
        for (int d = 0; d < D_N; ++d) {
            float w = ldx<F32>(Ws, d * H_N + h);
            #pragma unroll
            for (int q = 0; q < GT; ++q)
                acc[q] = fmaf(w, x0s[q * D_N + d], acc[q]);
        }
        #pragma unroll
        for (int q = 0; q < GT; ++q) {
            int gq = g0 + q;
            if (gq < G) skip[(size_t)gq * H_N + h] = acc[q];
        }
    }
}

__global__ __launch_bounds__(NTHR)
void ka_kernel(const int* __restrict__ nbr, const void* __restrict__ emb,
               const float* __restrict__ At, const float* __restrict__ c,
               const void* __restrict__ Ws,
               float* __restrict__ wl, float* __restrict__ skip, int G)
{
    __shared__ __align__(16) float x0s[GT * D_N];
    __shared__ int is_f32_s;
    int f32 = sniff_f32(emb, threadIdx.x, &is_f32_s);
    if (f32) ka_core<true >(blockIdx.x * GT, G, threadIdx.x, nbr, emb, At, c, Ws, wl, skip, x0s);
    else     ka_core<false>(blockIdx.x * GT, G, threadIdx.x, nbr, emb, At, c, Ws, wl, skip, x0s);
}

// ============ K2 (gather): scores -> softmax -> y, one graph per block, NO weight streams ============
template <bool F32>
__device__ __forceinline__ void kb_core(
    int g, int tid,
    const int* __restrict__ nbr, const int* __restrict__ adj,
    const void* __restrict__ emb,
    const float* __restrict__ wl, float* __restrict__ y, float* __restrict__ den,
    float* xs, float* wls, float* ps)
{
    // ---- prefetch everything independent up-front (maximize misses in flight) ----
    float wlv = (tid < D_N) ? wl[(size_t)g * D_N + tid] : 0.f;
    int mk = (tid < E_N) ? adj[(size_t)g * (E_N * E_N) + tid * E_N] : 0;  // mask[0,j]=adj[j,0]
    int idr[GATHER_IT];
    #pragma unroll
    for (int r = 0; r < GATHER_IT; ++r) {
        int i = tid + NTHR * r;
        idr[r] = (i < E_N * (D_N / 4)) ? nbr[g * E_N + i / 25] : 0;
    }
    if (tid < D_N) wls[tid] = wlv;

    // ---- gather 50 rows into LDS, transposed xs[d*XSTR + j] ----
    #pragma unroll
    for (int r = 0; r < GATHER_IT; ++r) {
        int i = tid + NTHR * r;
        if (i < E_N * (D_N / 4)) {
            int j  = i / 25;
            int d4 = i - j * 25;
            float4 v = ld4<F32>(emb, (long long)idr[r] * (D_N / 4) + d4);
            int d0 = d4 * 4;
            xs[(d0 + 0) * XSTR + j] = v.x;
            xs[(d0 + 1) * XSTR + j] = v.y;
            xs[(d0 + 2) * XSTR + j] = v.z;
            xs[(d0 + 3) * XSTR + j] = v.w;
        }
    }
    __syncthreads();

    // ---- wave 0: scores + masked softmax (shuffle reduce), pre-normalized ----
    if (tid < 64) {
        float s = 0.f;
        if (tid < E_N) {
            #pragma unroll 10
            for (int d = 0; d < D_N; ++d)
                s = fmaf(wls[d], xs[d * XSTR + tid], s);
            s *= 0.1f;                                      // 1/sqrt(H)
        }
        bool live = (tid < E_N) && (mk != 0);
        float m = live ? s : -3.0e38f;
        #pragma unroll
        for (int off = 32; off; off >>= 1)
            m = fmaxf(m, __shfl_xor(m, off));
        float e = live ? __expf(s - m) : 0.f;
        float dn = e;
        #pragma unroll
        for (int off = 32; off; off >>= 1)
            dn += __shfl_xor(dn, off);
        float inv = dn > 0.f ? 1.0f / dn : 0.f;
        if (tid < E_N) ps[tid] = e * inv;
        if (tid == 0)  den[g] = dn;
    }
    __syncthreads();

    // ---- y[d] = sum_j p_j x_j[d] ----
    if (tid < D_N) {
        float acc = 0.f;
        #pragma unroll 10
        for (int j = 0; j < E_N; ++j)
            acc = fmaf(ps[j], xs[tid * XSTR + j], acc);
        y[(size_t)g * D_N + tid] = acc;
    }
}

__global__ __launch_bounds__(NTHR)
void kb_kernel(const int* __restrict__ nbr, const int* __restrict__ adj,
               const void* __restrict__ emb,
               const float* __restrict__ wl, float* __restrict__ y,
               float* __restrict__ den, int G)
{
    __shared__ __align__(16) float xs[D_N * XSTR];   // 20.4 KB
    __shared__ __align__(16) float wls[D_N];
    __shared__ __align__(16) float ps[E_N];
    __shared__ int is_f32_s;
    int f32 = sniff_f32(emb, threadIdx.x, &is_f32_s);
    if (f32) kb_core<true >(blockIdx.x, threadIdx.x, nbr, adj, emb, wl, y, den, xs, wls, ps);
    else     kb_core<false>(blockIdx.x, threadIdx.x, nbr, adj, emb, wl, y, den, xs, wls, ps);
}

// ============ K3 (dense): out = bs + bv*[den>0] + y.Wv + skip  (GT graphs/block) ============
template <bool F32>
__device__ __forceinline__ void kc_core(
    int g0, int G, int tid,
    const void* __restrict__ Wv, const void* __restrict__ bv,
    const void* __restrict__ bs,
    const float* __restrict__ skip, const float* __restrict__ y,
    const float* __restrict__ den, void* __restrict__ out,
    float* ys, float* denf)
{
    if (tid < GT * (D_N / 4)) {
        int q = tid / (D_N / 4), d4 = tid - q * (D_N / 4);
        int gq = g0 + q; if (gq >= G) gq = G - 1;
        reinterpret_cast<float4*>(ys + q * D_N)[d4] =
            reinterpret_cast<const float4*>(y + (size_t)gq * D_N)[d4];
    }
    if (tid < GT) {
        int gq = g0 + tid; if (gq >= G) gq = G - 1;
        denf[tid] = den[gq];
    }
    __syncthreads();

    int half = tid >> 7;          // 0: graphs 0-3, 1: graphs 4-7
    int hh = tid & 127;
    if (hh < H_N) {
        int h = hh, qb = half * 4;
        float b   = ldx<F32>(bs, h);
        float bvv = ldx<F32>(bv, h);
        float acc[4];
        #pragma unroll
        for (int q2 = 0; q2 < 4; ++q2) {
            int gq = g0 + qb + q2; if (gq >= G) gq = G - 1;
            acc[q2] = b + (denf[qb + q2] > 0.f ? bvv : 0.f) + skip[(size_t)gq * H_N + h];
        }
        #pragma unroll 4
        for (int d = 0; d < D_N; ++d) {
            float w = ldx<F32>(Wv, d * H_N + h);
            #pragma unroll
            for (int q2 = 0; q2 < 4; ++q2)
                acc[q2] = fmaf(w, ys[(qb + q2) * D_N + d], acc[q2]);
        }
        #pragma unroll
        for (int q2 = 0; q2 < 4; ++q2) {
            int gq = g0 + qb + q2;
            if (gq < G) {
                size_t o = (size_t)gq * H_N + h;
                if (F32) reinterpret_cast<float*>(out)[o] = acc[q2];
                else     reinterpret_cast<unsigned short*>(out)[o] = f2bf(acc[q2]);
            }
        }
    }
}

__global__ __launch_bounds__(NTHR)
void kc_kernel(const void* __restrict__ Wv, const void* __restrict__ bv,
               const void* __restrict__ bs, const void* __restrict__ emb,
               const float* __restrict__ skip, const float* __restrict__ y,
               const float* __restrict__ den, void* __restrict__ out, int G)
{
    __shared__ __align__(16) float ys[GT * D_N];
    __shared__ float denf[GT];
    __shared__ int is_f32_s;
    int f32 = sniff_f32(emb, threadIdx.x, &is_f32_s);
    if (f32) kc_core<true >(blockIdx.x * GT, G, threadIdx.x, Wv, bv, bs, skip, y, den, out, ys, denf);
    else     kc_core<false>(blockIdx.x * GT, G, threadIdx.x, Wv, bv, bs, skip, y, den, out, ys, denf);
}

extern "C" void kernel_launch(void* const* d_in, const int* in_sizes, int n_in,
                              void* d_out, int out_size, void* d_ws, size_t ws_size,
                              hipStream_t stream) {
    const int* nbr = (const int*)d_in[0];
    const int* adj = (const int*)d_in[1];
    const void* emb = d_in[2];
    const void* Wq  = d_in[3];
    const void* bq  = d_in[4];
    const void* Wk  = d_in[5];   // d_in[6] = bk cancels inside softmax — unused
    const void* Wv  = d_in[7];
    const void* bv  = d_in[8];
    const void* Ws  = d_in[9];
    const void* bs  = d_in[10];

    const int G = in_sizes[0] / E_N;  // B*L = 3200

    // workspace (f32): At[10000] | c[100] | wl[G*100] | skip[G*100] | y[G*100] | den[G]
    // total = 10100 + 301*G floats  (G=3200 -> ~3.9 MB)
    float* At   = (float*)d_ws;
    float* c    = At + D_N * D_N;
    float* wl   = c + D_N;
    float* skip = wl + (size_t)G * D_N;
    float* y    = skip + (size_t)G * H_N;
    float* den  = y + (size_t)G * D_N;

    const int GB = (G + GT - 1) / GT;
    precomp_kernel<<<D_N, 128, 0, stream>>>(Wq, bq, Wk, emb, At, c);
    ka_kernel<<<GB, NTHR, 0, stream>>>(nbr, emb, At, c, Ws, wl, skip, G);
    kb_kernel<<<G, NTHR, 0, stream>>>(nbr, adj, emb, wl, y, den, G);
    kc_kernel<<<GB, NTHR, 0, stream>>>(Wv, bv, bs, emb, skip, y, den, d_out, G);
}

// Round 4
// 185.872 us; speedup vs baseline: 1.1879x; 1.0216x over previous
//
#include <hip/hip_runtime.h>
#include <math.h>

#define E_N 50
#define D_N 100
#define H_N 100
#define NTHR 256
#define GG (E_N * E_N)   // 2500: ints per adj graph; also u32-chunks per gathered graph (bf16)

typedef unsigned int u32;
typedef unsigned short u16;
typedef __attribute__((address_space(1))) const void gvoid;
typedef __attribute__((address_space(3))) void lvoid;

__device__ __forceinline__ float bf2f(u32 s16) { return __uint_as_float(s16 << 16); }

__device__ __forceinline__ u16 f2bf(float f) {
    u32 u = __float_as_uint(f);
    return (u16)((u + 0x7FFFu + ((u >> 16) & 1u)) >> 16);  // round-nearest-even
}

template <bool F32>
__device__ __forceinline__ float ldx(const void* p, int i) {
    if (F32) return reinterpret_cast<const float*>(p)[i];
    return bf2f(reinterpret_cast<const u16*>(p)[i]);
}

template <bool F32>
__device__ __forceinline__ float4 ld4(const void* p, long long i4) {
    if (F32) return reinterpret_cast<const float4*>(p)[i4];
    uint2 v = reinterpret_cast<const uint2*>(p)[i4];
    float4 f;
    f.x = bf2f(v.x & 0xFFFFu);
    f.y = bf2f(v.x >> 16);
    f.z = bf2f(v.y & 0xFFFFu);
    f.w = bf2f(v.y >> 16);
    return f;
}

// dtype detector: even halfwords of emb decode sane iff data is bf16
__device__ __forceinline__ int sniff_f32(const void* emb, int tid, int* slot) {
    if (tid < 64) {
        u16 hw = reinterpret_cast<const u16*>(emb)[tid * 2];
        float v = bf2f(hw);
        float a = fabsf(v);
        int sane = (v == 0.f) || (a >= 1e-4f && a <= 8.0f);
        unsigned long long ball = __ballot(sane);
        if (tid == 0) *slot = (__popcll(ball) < 32) ? 1 : 0;
    }
    __syncthreads();
    return *slot;
}

// ============ K0: At[dp*100+d] = sum_h Wk[d,h]Wq[dp,h]; c[d] = sum_h Wk[d,h]bq[h] ============
template <bool F32>
__device__ __forceinline__ void precomp_core(
    int dp, int tid, const void* __restrict__ Wq, const void* __restrict__ bq,
    const void* __restrict__ Wk, float* __restrict__ At, float* __restrict__ c,
    float* wq_s, float* bq_s)
{
    if (tid < H_N) wq_s[tid] = ldx<F32>(Wq, dp * H_N + tid);
    if (dp == 0 && tid < H_N) bq_s[tid] = ldx<F32>(bq, tid);
    __syncthreads();
    if (tid < D_N) {
        float a0 = 0.f, a1 = 0.f, a2 = 0.f, a3 = 0.f;
        #pragma unroll
        for (int h4 = 0; h4 < H_N / 4; ++h4) {
            float4 w = ld4<F32>(Wk, (long long)tid * (H_N / 4) + h4);
            a0 = fmaf(w.x, wq_s[h4 * 4 + 0], a0);
            a1 = fmaf(w.y, wq_s[h4 * 4 + 1], a1);
            a2 = fmaf(w.z, wq_s[h4 * 4 + 2], a2);
            a3 = fmaf(w.w, wq_s[h4 * 4 + 3], a3);
        }
        At[dp * D_N + tid] = (a0 + a1) + (a2 + a3);
        if (dp == 0) {
            float c0 = 0.f, c1 = 0.f, c2 = 0.f, c3 = 0.f;
            #pragma unroll
            for (int h4 = 0; h4 < H_N / 4; ++h4) {
                float4 w = ld4<F32>(Wk, (long long)tid * (H_N / 4) + h4);
                c0 = fmaf(w.x, bq_s[h4 * 4 + 0], c0);
                c1 = fmaf(w.y, bq_s[h4 * 4 + 1], c1);
                c2 = fmaf(w.z, bq_s[h4 * 4 + 2], c2);
                c3 = fmaf(w.w, bq_s[h4 * 4 + 3], c3);
            }
            c[tid] = (c0 + c1) + (c2 + c3);
        }
    }
}

__global__ __launch_bounds__(128)
void precomp_kernel(const void* __restrict__ Wq, const void* __restrict__ bq,
                    const void* __restrict__ Wk, const void* __restrict__ emb,
                    float* __restrict__ At, float* __restrict__ c)
{
    __shared__ float wq_s[H_N];
    __shared__ float bq_s[H_N];
    __shared__ int is_f32_s;
    int f32 = sniff_f32(emb, threadIdx.x, &is_f32_s);
    if (f32) precomp_core<true >(blockIdx.x, threadIdx.x, Wq, bq, Wk, At, c, wq_s, bq_s);
    else     precomp_core<false>(blockIdx.x, threadIdx.x, Wq, bq, Wk, At, c, wq_s, bq_s);
}

// ============ fused main: 2 graphs per block (bf16) ============
// per graph: w = A x0 + c; s_j = 0.1*(x_j.w); masked softmax -> p; y = sum p x;
//            out = bs + bv*[any edge] + y.Wv + x0.Ws
// xs kept as RAW bf16 pairs in LDS (u32 per 2 elems), filled by global_load_lds
// (linear chunk index i -> LDS word i: satisfies the wave-uniform-base + lane*4 rule).
// adj is symmetric (max(a,a^T,I)) => mask[0,j] = adj[j,0] = adj[0,j]: read ROW 0 (4 lines, not 50).
__device__ __forceinline__ void core_bf16(
    int g0, int g1, int G, int tid,
    const int* __restrict__ nbr, const int* __restrict__ adj,
    const void* __restrict__ emb,
    const float* __restrict__ At, const float* __restrict__ c,
    const void* __restrict__ Wv, const void* __restrict__ bv,
    const void* __restrict__ Ws, const void* __restrict__ bs,
    void* __restrict__ out,
    u32* xsu, float* wls, float* ps, float* ys, float* dens)
{
    // ---- mask: wave w holds graph w's mask (row 0 of adj, consecutive) ----
    int mk = 0;
    {
        int w = tid >> 6, j = tid & 63;
        if (w < 2 && j < E_N)
            mk = adj[(size_t)(w ? g1 : g0) * GG + j];
    }

    const u16* e16 = (const u16*)emb;
    // ---- graph 0: ids then fire-and-forget gather (50 rows x 50 u32-chunks) ----
    {
        int idr[10];
        #pragma unroll
        for (int r = 0; r < 10; ++r) {
            int i = tid + NTHR * r;
            idr[r] = (i < GG) ? nbr[g0 * E_N + i / 50] : 0;
        }
        #pragma unroll
        for (int r = 0; r < 10; ++r) {
            int i = tid + NTHR * r;
            if (i < GG) {
                int j = i / 50, cc = i - j * 50;
                const u16* ga = e16 + (size_t)idr[r] * D_N + cc * 2;
                u32* lb = xsu + (NTHR * r + (tid & ~63));     // wave-uniform base
                __builtin_amdgcn_global_load_lds((gvoid*)ga, (lvoid*)lb, 4, 0, 0);
            }
        }
    }
    // ---- graph 1 (register reuse keeps VGPR low) ----
    {
        int idr[10];
        #pragma unroll
        for (int r = 0; r < 10; ++r) {
            int i = tid + NTHR * r;
            idr[r] = (i < GG) ? nbr[g1 * E_N + i / 50] : 0;
        }
        #pragma unroll
        for (int r = 0; r < 10; ++r) {
            int i = tid + NTHR * r;
            if (i < GG) {
                int j = i / 50, cc = i - j * 50;
                const u16* ga = e16 + (size_t)idr[r] * D_N + cc * 2;
                u32* lb = xsu + GG + (NTHR * r + (tid & ~63));
                __builtin_amdgcn_global_load_lds((gvoid*)ga, (lvoid*)lb, 4, 0, 0);
            }
        }
    }
    __syncthreads();   // drains vmcnt -> all rows in LDS

    // ---- w[q][d] = c[d] + sum_dp At[dp,d] * x0_q[dp]  (At L2-resident, coalesced) ----
    if (tid < 2 * D_N) {
        int q = tid / D_N, d = tid - q * D_N;
        float acc = c[d];
        const u32* x0 = xsu + q * GG;                         // row 0
        #pragma unroll 4
        for (int dp = 0; dp < D_N; dp += 2) {
            u32 xp = x0[dp >> 1];                             // LDS broadcast (2-way)
            acc = fmaf(At[dp * D_N + d],       bf2f(xp & 0xFFFFu), acc);
            acc = fmaf(At[(dp + 1) * D_N + d], bf2f(xp >> 16),     acc);
        }
        wls[q * D_N + d] = acc;
    }
    __syncthreads();

    // ---- scores + masked softmax: wave w handles graph w (in-wave shuffle reduce) ----
    if (tid < 128) {
        int w = tid >> 6, j = tid & 63;
        float s = 0.f;
        if (j < E_N) {
            const u32* xr = xsu + w * GG + j * 50;
            const float* wv = wls + w * D_N;
            #pragma unroll 5
            for (int d2 = 0; d2 < 50; ++d2) {
                u32 xp = xr[d2];
                s = fmaf(bf2f(xp & 0xFFFFu), wv[2 * d2],     s);
                s = fmaf(bf2f(xp >> 16),     wv[2 * d2 + 1], s);
            }
            s *= 0.1f;                                        // 1/sqrt(H)
        }
        bool live = (j < E_N) && (mk != 0);
        float m = live ? s : -3.0e38f;
        #pragma unroll
        for (int off = 32; off; off >>= 1)
            m = fmaxf(m, __shfl_xor(m, off));
        float e = live ? __expf(s - m) : 0.f;
        float dn = e;
        #pragma unroll
        for (int off = 32; off; off >>= 1)
            dn += __shfl_xor(dn, off);
        float inv = dn > 0.f ? 1.0f / dn : 0.f;
        if (j < E_N) ps[w * E_N + j] = e * inv;               // pre-normalized
        if (j == 0)  dens[w] = dn;
    }
    __syncthreads();

    // ---- y[q][d] = sum_j p_j x_j[d]  (lane-pairs share addr: conflict-free) ----
    if (tid < 2 * D_N) {
        int q = tid / D_N, d = tid - q * D_N;
        const u32* xq = xsu + q * GG + (d >> 1);
        int hi = d & 1;
        float acc = 0.f;
        #pragma unroll 10
        for (int j = 0; j < E_N; ++j) {
            u32 xp = xq[j * 50];
            acc = fmaf(ps[q * E_N + j], bf2f(hi ? (xp >> 16) : (xp & 0xFFFFu)), acc);
        }
        ys[q * D_N + d] = acc;
    }
    __syncthreads();

    // ---- out[q][h] = bs + bv*[den>0] + y.Wv[:,h] + x0.Ws[:,h]  (Wv/Ws L2-resident) ----
    if (tid < 2 * H_N) {
        int q = tid / H_N, h = tid - q * H_N;
        float flag = dens[q] > 0.f ? 1.f : 0.f;
        float acc = ldx<false>(bs, h) + ldx<false>(bv, h) * flag;
        const u32* x0 = xsu + q * GG;
        const float* yq = ys + q * D_N;
        #pragma unroll 2
        for (int dp = 0; dp < D_N; dp += 2) {
            u32 xp = x0[dp >> 1];
            acc = fmaf(yq[dp],     ldx<false>(Wv, dp * H_N + h),       acc);
            acc = fmaf(yq[dp + 1], ldx<false>(Wv, (dp + 1) * H_N + h), acc);
            acc = fmaf(bf2f(xp & 0xFFFFu), ldx<false>(Ws, dp * H_N + h),       acc);
            acc = fmaf(bf2f(xp >> 16),     ldx<false>(Ws, (dp + 1) * H_N + h), acc);
        }
        if (g0 + q < G) {
            size_t o = (size_t)(q ? g1 : g0) * H_N + h;
            ((u16*)out)[o] = f2bf(acc);
        }
    }
}

// ---- f32 fallback: same structure, one graph at a time (full-f32 LDS reuse) ----
__device__ __forceinline__ void core_f32_one(
    int g, int valid, int tid,
    const int* __restrict__ nbr, const int* __restrict__ adj,
    const void* __restrict__ emb,
    const float* __restrict__ At, const float* __restrict__ c,
    const void* __restrict__ Wv, const void* __restrict__ bv,
    const void* __restrict__ Ws, const void* __restrict__ bs,
    void* __restrict__ out,
    float* xs /*[50][100]*/, float* wls, float* ps, float* ys, float* dens)
{
    int mk = (tid < E_N) ? adj[(size_t)g * GG + tid] : 0;     // symmetric row-0 read
    const float* ef = (const float*)emb;
    {
        int idr[5];
        #pragma unroll
        for (int r = 0; r < 5; ++r) {
            int i = tid + NTHR * r;                           // 16B chunks, 25/row, 1250 total
            idr[r] = (i < E_N * 25) ? nbr[g * E_N + i / 25] : 0;
        }
        #pragma unroll
        for (int r = 0; r < 5; ++r) {
            int i = tid + NTHR * r;
            if (i < E_N * 25) {
                int j = i / 25, d4 = i - j * 25;
                const float* ga = ef + (size_t)idr[r] * D_N + d4 * 4;
                float* lb = xs + 4 * (NTHR * r + (tid & ~63));
                __builtin_amdgcn_global_load_lds((gvoid*)ga, (lvoid*)lb, 16, 0, 0);
            }
        }
    }
    __syncthreads();

    if (tid < D_N) {
        float acc = c[tid];
        #pragma unroll 4
        for (int dp = 0; dp < D_N; ++dp)
            acc = fmaf(At[dp * D_N + tid], xs[dp], acc);      // x0 = xs row 0
        wls[tid] = acc;
    }
    __syncthreads();

    if (tid < 64) {
        float s = 0.f;
        if (tid < E_N) {
            #pragma unroll 10
            for (int d = 0; d < D_N; ++d)
                s = fmaf(wls[d], xs[tid * D_N + d], s);
            s *= 0.1f;
        }
        bool live = (tid < E_N) && (mk != 0);
        float m = live ? s : -3.0e38f;
        #pragma unroll
        for (int off = 32; off; off >>= 1)
            m = fmaxf(m, __shfl_xor(m, off));
        float e = live ? __expf(s - m) : 0.f;
        float dn = e;
        #pragma unroll
        for (int off = 32; off; off >>= 1)
            dn += __shfl_xor(dn, off);
        float inv = dn > 0.f ? 1.0f / dn : 0.f;
        if (tid < E_N) ps[tid] = e * inv;
        if (tid == 0)  dens[0] = dn;
    }
    __syncthreads();

    if (tid < D_N) {
        float acc = 0.f;
        #pragma unroll 10
        for (int j = 0; j < E_N; ++j)
            acc = fmaf(ps[j], xs[j * D_N + tid], acc);
        ys[tid] = acc;
    }
    __syncthreads();

    if (tid < H_N && valid) {
        float flag = dens[0] > 0.f ? 1.f : 0.f;
        float acc = ldx<true>(bs, tid) + ldx<true>(bv, tid) * flag;
        #pragma unroll 4
        for (int d = 0; d < D_N; ++d) {
            acc = fmaf(ys[d],  ldx<true>(Wv, d * H_N + tid), acc);
            acc = fmaf(xs[d],  ldx<true>(Ws, d * H_N + tid), acc);
        }
        ((float*)out)[(size_t)g * H_N + tid] = acc;
    }
    __syncthreads();   // protect xs before next graph's gather
}

__global__ __launch_bounds__(NTHR, 7)   // keep VGPR <= ~72 so LDS (22 KB -> 7 blocks/CU) binds
void fused2_kernel(const int* __restrict__ nbr, const int* __restrict__ adj,
                   const void* __restrict__ emb,
                   const float* __restrict__ At, const float* __restrict__ c,
                   const void* __restrict__ Wv, const void* __restrict__ bv,
                   const void* __restrict__ Ws, const void* __restrict__ bs,
                   void* __restrict__ out, int G)
{
    __shared__ __align__(16) u32   xsu[2 * GG];     // 20 KB: bf16 2 graphs / f32 1 graph
    __shared__ __align__(16) float wls[2 * D_N];
    __shared__ __align__(16) float ps [2 * E_N];
    __shared__ __align__(16) float ys [2 * D_N];
    __shared__ float dens[2];
    __shared__ int is_f32_s;

    int tid = threadIdx.x;
    int g0 = blockIdx.x * 2;
    int g1 = (g0 + 1 < G) ? g0 + 1 : G - 1;
    int f32 = sniff_f32(emb, tid, &is_f32_s);

    if (!f32) {
        core_bf16(g0, g1, G, tid, nbr, adj, emb, At, c, Wv, bv, Ws, bs, out,
                  xsu, wls, ps, ys, dens);
    } else {
        float* xsf = reinterpret_cast<float*>(xsu);           // 5000 floats = [50][100]
        core_f32_one(g0, 1, tid, nbr, adj, emb, At, c, Wv, bv, Ws, bs, out,
                     xsf, wls, ps, ys, dens);
        core_f32_one(g1, g0 + 1 < G, tid, nbr, adj, emb, At, c, Wv, bv, Ws, bs, out,
                     xsf, wls, ps, ys, dens);
    }
}

extern "C" void kernel_launch(void* const* d_in, const int* in_sizes, int n_in,
                              void* d_out, int out_size, void* d_ws, size_t ws_size,
                              hipStream_t stream) {
    const int* nbr = (const int*)d_in[0];
    const int* adj = (const int*)d_in[1];
    const void* emb = d_in[2];
    const void* Wq  = d_in[3];
    const void* bq  = d_in[4];
    const void* Wk  = d_in[5];   // d_in[6] = bk cancels inside softmax — unused
    const void* Wv  = d_in[7];
    const void* bv  = d_in[8];
    const void* Ws  = d_in[9];
    const void* bs  = d_in[10];

    const int G = in_sizes[0] / E_N;  // B*L = 3200

    // workspace (f32): At[10000] | c[100]  (40.4 KB)
    float* At = (float*)d_ws;
    float* c  = At + D_N * D_N;

    precomp_kernel<<<D_N, 128, 0, stream>>>(Wq, bq, Wk, emb, At, c);
    fused2_kernel<<<(G + 1) / 2, NTHR, 0, stream>>>(nbr, adj, emb, At, c,
                                                    Wv, bv, Ws, bs, d_out, G);
}

// Round 5
// 185.030 us; speedup vs baseline: 1.1933x; 1.0045x over previous
//
#include <hip/hip_runtime.h>
#include <math.h>

#define E_N 50
#define D_N 100
#define H_N 100
#define NTHR 256
#define GG (E_N * E_N)   // 2500: ints per adj graph; also u32-chunks per gathered bf16 graph

typedef unsigned int u32;
typedef unsigned short u16;
typedef __attribute__((address_space(1))) const void gvoid;
typedef __attribute__((address_space(3))) void lvoid;

__device__ __forceinline__ float bf2f(u32 s16) { return __uint_as_float(s16 << 16); }

__device__ __forceinline__ u16 f2bf(float f) {
    u32 u = __float_as_uint(f);
    return (u16)((u + 0x7FFFu + ((u >> 16) & 1u)) >> 16);  // round-nearest-even
}

template <bool F32>
__device__ __forceinline__ float ldx(const void* p, int i) {
    if (F32) return reinterpret_cast<const float*>(p)[i];
    return bf2f(reinterpret_cast<const u16*>(p)[i]);
}

template <bool F32>
__device__ __forceinline__ float4 ld4(const void* p, long long i4) {
    if (F32) return reinterpret_cast<const float4*>(p)[i4];
    uint2 v = reinterpret_cast<const uint2*>(p)[i4];
    float4 f;
    f.x = bf2f(v.x & 0xFFFFu);
    f.y = bf2f(v.x >> 16);
    f.z = bf2f(v.y & 0xFFFFu);
    f.w = bf2f(v.y >> 16);
    return f;
}

// dtype detector: even halfwords of emb decode sane iff data is bf16
__device__ __forceinline__ int sniff_f32(const void* emb, int tid, int* slot) {
    if (tid < 64) {
        u16 hw = reinterpret_cast<const u16*>(emb)[tid * 2];
        float v = bf2f(hw);
        float a = fabsf(v);
        int sane = (v == 0.f) || (a >= 1e-4f && a <= 8.0f);
        unsigned long long ball = __ballot(sane);
        if (tid == 0) *slot = (__popcll(ball) < 32) ? 1 : 0;
    }
    __syncthreads();
    return *slot;
}

// LDS-visibility barrier WITHOUT draining vmcnt (keeps g1's gathers in flight)
__device__ __forceinline__ void bar_lds() {
    asm volatile("s_waitcnt lgkmcnt(0)" ::: "memory");
    __builtin_amdgcn_sched_barrier(0);
    __builtin_amdgcn_s_barrier();
    __builtin_amdgcn_sched_barrier(0);
}

// ============ K0: At[dp*100+d] = sum_h Wk[d,h]Wq[dp,h]; c[d] = sum_h Wk[d,h]bq[h] ============
template <bool F32>
__device__ __forceinline__ void precomp_core(
    int dp, int tid, const void* __restrict__ Wq, const void* __restrict__ bq,
    const void* __restrict__ Wk, float* __restrict__ At, float* __restrict__ c,
    float* wq_s, float* bq_s)
{
    if (tid < H_N) wq_s[tid] = ldx<F32>(Wq, dp * H_N + tid);
    if (dp == 0 && tid < H_N) bq_s[tid] = ldx<F32>(bq, tid);
    __syncthreads();
    if (tid < D_N) {
        float a0 = 0.f, a1 = 0.f, a2 = 0.f, a3 = 0.f;
        #pragma unroll
        for (int h4 = 0; h4 < H_N / 4; ++h4) {
            float4 w = ld4<F32>(Wk, (long long)tid * (H_N / 4) + h4);
            a0 = fmaf(w.x, wq_s[h4 * 4 + 0], a0);
            a1 = fmaf(w.y, wq_s[h4 * 4 + 1], a1);
            a2 = fmaf(w.z, wq_s[h4 * 4 + 2], a2);
            a3 = fmaf(w.w, wq_s[h4 * 4 + 3], a3);
        }
        At[dp * D_N + tid] = (a0 + a1) + (a2 + a3);
        if (dp == 0) {
            float c0 = 0.f, c1 = 0.f, c2 = 0.f, c3 = 0.f;
            #pragma unroll
            for (int h4 = 0; h4 < H_N / 4; ++h4) {
                float4 w = ld4<F32>(Wk, (long long)tid * (H_N / 4) + h4);
                c0 = fmaf(w.x, bq_s[h4 * 4 + 0], c0);
                c1 = fmaf(w.y, bq_s[h4 * 4 + 1], c1);
                c2 = fmaf(w.z, bq_s[h4 * 4 + 2], c2);
                c3 = fmaf(w.w, bq_s[h4 * 4 + 3], c3);
            }
            c[tid] = (c0 + c1) + (c2 + c3);
        }
    }
}

__global__ __launch_bounds__(128)
void precomp_kernel(const void* __restrict__ Wq, const void* __restrict__ bq,
                    const void* __restrict__ Wk, const void* __restrict__ emb,
                    float* __restrict__ At, float* __restrict__ c)
{
    __shared__ float wq_s[H_N];
    __shared__ float bq_s[H_N];
    __shared__ int is_f32_s;
    int f32 = sniff_f32(emb, threadIdx.x, &is_f32_s);
    if (f32) precomp_core<true >(blockIdx.x, threadIdx.x, Wq, bq, Wk, At, c, wq_s, bq_s);
    else     precomp_core<false>(blockIdx.x, threadIdx.x, Wq, bq, Wk, At, c, wq_s, bq_s);
}

// ============ per-graph dense pipeline (bf16 path), graph slot q, rows in xq ============
// wl = A x0 + c; s_j = 0.1 x_j.wl; masked softmax (wave q) -> ps; y = sum p x;
// out = bs + bv*[den>0] + y.Wv + x0.Ws
__device__ __forceinline__ void dense_one(
    int q, int gq, int valid, int tid, int mk,
    const float* __restrict__ At, const float* __restrict__ c,
    const void* __restrict__ Wv, const void* __restrict__ bv,
    const void* __restrict__ Ws, const void* __restrict__ bs,
    void* __restrict__ out,
    const u32* xq, float* wls, float* ps, float* ys, float* dens)
{
    // ---- wl[d] = c[d] + sum_dp At[dp,d] * x0[dp] ----
    if (tid < D_N) {
        float acc = c[tid];
        #pragma unroll 4
        for (int dp = 0; dp < D_N; dp += 2) {
            u32 xp = xq[dp >> 1];                             // LDS broadcast
            acc = fmaf(At[dp * D_N + tid],       bf2f(xp & 0xFFFFu), acc);
            acc = fmaf(At[(dp + 1) * D_N + tid], bf2f(xp >> 16),     acc);
        }
        wls[tid] = acc;
    }
    bar_lds();

    // ---- scores + masked softmax on wave q (holds graph q's mask) ----
    if ((tid >> 6) == q) {
        int j = tid & 63;
        float s = 0.f;
        if (j < E_N) {
            const u32* xr = xq + j * 50;
            #pragma unroll 5
            for (int d2 = 0; d2 < 50; ++d2) {
                u32 xp = xr[d2];
                s = fmaf(bf2f(xp & 0xFFFFu), wls[2 * d2],     s);
                s = fmaf(bf2f(xp >> 16),     wls[2 * d2 + 1], s);
            }
            s *= 0.1f;                                        // 1/sqrt(H)
        }
        bool live = (j < E_N) && (mk != 0);
        float m = live ? s : -3.0e38f;
        #pragma unroll
        for (int off = 32; off; off >>= 1)
            m = fmaxf(m, __shfl_xor(m, off));
        float e = live ? __expf(s - m) : 0.f;
        float dn = e;
        #pragma unroll
        for (int off = 32; off; off >>= 1)
            dn += __shfl_xor(dn, off);
        float inv = dn > 0.f ? 1.0f / dn : 0.f;
        if (j < E_N) ps[j] = e * inv;                         // pre-normalized
        if (j == 0)  dens[0] = dn;
    }
    bar_lds();

    // ---- y[d] = sum_j p_j x_j[d]  (lane pairs share LDS word: conflict-free) ----
    if (tid < D_N) {
        const u32* xd = xq + (tid >> 1);
        int hi = tid & 1;
        float acc = 0.f;
        #pragma unroll 10
        for (int j = 0; j < E_N; ++j) {
            u32 xp = xd[j * 50];
            acc = fmaf(ps[j], bf2f(hi ? (xp >> 16) : (xp & 0xFFFFu)), acc);
        }
        ys[tid] = acc;
    }
    bar_lds();

    // ---- out[h] = bs + bv*[den>0] + y.Wv[:,h] + x0.Ws[:,h] ----
    if (tid < H_N && valid) {
        float flag = dens[0] > 0.f ? 1.f : 0.f;
        float acc = ldx<false>(bs, tid) + ldx<false>(bv, tid) * flag;
        #pragma unroll 2
        for (int dp = 0; dp < D_N; dp += 2) {
            u32 xp = xq[dp >> 1];
            acc = fmaf(ys[dp],     ldx<false>(Wv, dp * H_N + tid),       acc);
            acc = fmaf(ys[dp + 1], ldx<false>(Wv, (dp + 1) * H_N + tid), acc);
            acc = fmaf(bf2f(xp & 0xFFFFu), ldx<false>(Ws, dp * H_N + tid),       acc);
            acc = fmaf(bf2f(xp >> 16),     ldx<false>(Ws, (dp + 1) * H_N + tid), acc);
        }
        ((u16*)out)[(size_t)gq * H_N + tid] = f2bf(acc);
    }
}

// ============ fused main (bf16): 2 graphs/block, g0 compute overlaps g1 misses ============
__device__ __forceinline__ void core_bf16(
    int g0, int g1, int valid1, int tid,
    const int* __restrict__ nbr, const int* __restrict__ adj,
    const void* __restrict__ emb,
    const float* __restrict__ At, const float* __restrict__ c,
    const void* __restrict__ Wv, const void* __restrict__ bv,
    const void* __restrict__ Ws, const void* __restrict__ bs,
    void* __restrict__ out,
    u32* xsu, float* wls, float* ps, float* ys, float* dens)
{
    // ---- mask first (oldest in vmcnt queue): wave w holds graph w's row-0 mask ----
    int w = tid >> 6, jj = tid & 63;
    int mk = 0;
    if (w < 2 && jj < E_N)
        mk = adj[(size_t)(w ? g1 : g0) * GG + jj];            // adj symmetric: row0 == col0

    // ---- ALL ids up front (so no later waitcnt drains the gathers) ----
    int idr[20];
    #pragma unroll
    for (int r = 0; r < 10; ++r) {
        int i = tid + NTHR * r;
        idr[r]      = (i < GG) ? nbr[g0 * E_N + i / 50] : 0;
        idr[10 + r] = (i < GG) ? nbr[g1 * E_N + i / 50] : 0;
    }
    asm volatile("" :: "v"(mk));   // force mk consumed -> its load retires before gathers
    __builtin_amdgcn_sched_barrier(0);

    const u16* e16 = (const u16*)emb;
    // ---- g0 gathers (10 wave-instrs) ----
    #pragma unroll
    for (int r = 0; r < 10; ++r) {
        int i = tid + NTHR * r;
        if (i < GG) {
            int cc = i % 50;
            const u16* ga = e16 + (size_t)idr[r] * D_N + cc * 2;
            u32* lb = xsu + (NTHR * r + (tid & ~63));         // wave-uniform base + lane*4
            __builtin_amdgcn_global_load_lds((gvoid*)ga, (lvoid*)lb, 4, 0, 0);
        }
    }
    __builtin_amdgcn_sched_barrier(0);                        // pin g0-before-g1 issue order
    // ---- g1 gathers (10 wave-instrs, stay in flight through g0 compute) ----
    #pragma unroll
    for (int r = 0; r < 10; ++r) {
        int i = tid + NTHR * r;
        if (i < GG) {
            int cc = i % 50;
            const u16* ga = e16 + (size_t)idr[10 + r] * D_N + cc * 2;
            u32* lb = xsu + GG + (NTHR * r + (tid & ~63));
            __builtin_amdgcn_global_load_lds((gvoid*)ga, (lvoid*)lb, 4, 0, 0);
        }
    }
    __builtin_amdgcn_sched_barrier(0);

    // ---- stage 1: wait ONLY g0's 10 oldest; g1's 10 remain outstanding ----
    asm volatile("s_waitcnt vmcnt(10)" ::: "memory");
    __builtin_amdgcn_sched_barrier(0);
    __builtin_amdgcn_s_barrier();
    __builtin_amdgcn_sched_barrier(0);

    dense_one(0, g0, 1, tid, mk, At, c, Wv, bv, Ws, bs, out, xsu, wls, ps, ys, dens);

    // ---- stage 2: full drain (g1 gathers + g0 store) ----
    __syncthreads();
    dense_one(1, g1, valid1, tid, mk, At, c, Wv, bv, Ws, bs, out, xsu + GG, wls, ps, ys, dens);
}

// ---- f32 fallback: one graph at a time (verified in R4) ----
__device__ __forceinline__ void core_f32_one(
    int g, int valid, int tid,
    const int* __restrict__ nbr, const int* __restrict__ adj,
    const void* __restrict__ emb,
    const float* __restrict__ At, const float* __restrict__ c,
    const void* __restrict__ Wv, const void* __restrict__ bv,
    const void* __restrict__ Ws, const void* __restrict__ bs,
    void* __restrict__ out,
    float* xs /*[50][100]*/, float* wls, float* ps, float* ys, float* dens)
{
    int mk = (tid < E_N) ? adj[(size_t)g * GG + tid] : 0;     // symmetric row-0 read
    const float* ef = (const float*)emb;
    {
        int idr[5];
        #pragma unroll
        for (int r = 0; r < 5; ++r) {
            int i = tid + NTHR * r;                           // 16B chunks, 25/row, 1250 total
            idr[r] = (i < E_N * 25) ? nbr[g * E_N + i / 25] : 0;
        }
        #pragma unroll
        for (int r = 0; r < 5; ++r) {
            int i = tid + NTHR * r;
            if (i < E_N * 25) {
                int j = i / 25, d4 = i - j * 25;
                const float* ga = ef + (size_t)idr[r] * D_N + d4 * 4;
                float* lb = xs + 4 * (NTHR * r + (tid & ~63));
                __builtin_amdgcn_global_load_lds((gvoid*)ga, (lvoid*)lb, 16, 0, 0);
            }
        }
    }
    __syncthreads();

    if (tid < D_N) {
        float acc = c[tid];
        #pragma unroll 4
        for (int dp = 0; dp < D_N; ++dp)
            acc = fmaf(At[dp * D_N + tid], xs[dp], acc);      // x0 = xs row 0
        wls[tid] = acc;
    }
    __syncthreads();

    if (tid < 64) {
        float s = 0.f;
        if (tid < E_N) {
            #pragma unroll 10
            for (int d = 0; d < D_N; ++d)
                s = fmaf(wls[d], xs[tid * D_N + d], s);
            s *= 0.1f;
        }
        bool live = (tid < E_N) && (mk != 0);
        float m = live ? s : -3.0e38f;
        #pragma unroll
        for (int off = 32; off; off >>= 1)
            m = fmaxf(m, __shfl_xor(m, off));
        float e = live ? __expf(s - m) : 0.f;
        float dn = e;
        #pragma unroll
        for (int off = 32; off; off >>= 1)
            dn += __shfl_xor(dn, off);
        float inv = dn > 0.f ? 1.0f / dn : 0.f;
        if (tid < E_N) ps[tid] = e * inv;
        if (tid == 0)  dens[0] = dn;
    }
    __syncthreads();

    if (tid < D_N) {
        float acc = 0.f;
        #pragma unroll 10
        for (int j = 0; j < E_N; ++j)
            acc = fmaf(ps[j], xs[j * D_N + tid], acc);
        ys[tid] = acc;
    }
    __syncthreads();

    if (tid < H_N && valid) {
        float flag = dens[0] > 0.f ? 1.f : 0.f;
        float acc = ldx<true>(bs, tid) + ldx<true>(bv, tid) * flag;
        #pragma unroll 4
        for (int d = 0; d < D_N; ++d) {
            acc = fmaf(ys[d], ldx<true>(Wv, d * H_N + tid), acc);
            acc = fmaf(xs[d], ldx<true>(Ws, d * H_N + tid), acc);
        }
        ((float*)out)[(size_t)g * H_N + tid] = acc;
    }
    __syncthreads();   // protect xs before next graph's gather
}

__global__ __launch_bounds__(NTHR, 7)   // LDS ~21 KB -> 7 blocks/CU; cap VGPR so LDS binds
void fused2_kernel(const int* __restrict__ nbr, const int* __restrict__ adj,
                   const void* __restrict__ emb,
                   const float* __restrict__ At, const float* __restrict__ c,
                   const void* __restrict__ Wv, const void* __restrict__ bv,
                   const void* __restrict__ Ws, const void* __restrict__ bs,
                   void* __restrict__ out, int G)
{
    __shared__ __align__(16) u32   xsu[2 * GG];     // 20 KB: bf16 2 graphs / f32 1 graph
    __shared__ __align__(16) float wls[D_N];
    __shared__ __align__(16) float ps [E_N];
    __shared__ __align__(16) float ys [D_N];
    __shared__ float dens[1];
    __shared__ int is_f32_s;

    int tid = threadIdx.x;
    int g0 = blockIdx.x * 2;
    int g1 = (g0 + 1 < G) ? g0 + 1 : G - 1;
    int f32 = sniff_f32(emb, tid, &is_f32_s);

    if (!f32) {
        core_bf16(g0, g1, (g0 + 1 < G) ? 1 : 0, tid, nbr, adj, emb, At, c,
                  Wv, bv, Ws, bs, out, xsu, wls, ps, ys, dens);
    } else {
        float* xsf = reinterpret_cast<float*>(xsu);           // 5000 floats = [50][100]
        core_f32_one(g0, 1, tid, nbr, adj, emb, At, c, Wv, bv, Ws, bs, out,
                     xsf, wls, ps, ys, dens);
        core_f32_one(g1, g0 + 1 < G, tid, nbr, adj, emb, At, c, Wv, bv, Ws, bs, out,
                     xsf, wls, ps, ys, dens);
    }
}

extern "C" void kernel_launch(void* const* d_in, const int* in_sizes, int n_in,
                              void* d_out, int out_size, void* d_ws, size_t ws_size,
                              hipStream_t stream) {
    const int* nbr = (const int*)d_in[0];
    const int* adj = (const int*)d_in[1];
    const void* emb = d_in[2];
    const void* Wq  = d_in[3];
    const void* bq  = d_in[4];
    const void* Wk  = d_in[5];   // d_in[6] = bk cancels inside softmax — unused
    const void* Wv  = d_in[7];
    const void* bv  = d_in[8];
    const void* Ws  = d_in[9];
    const void* bs  = d_in[10];

    const int G = in_sizes[0] / E_N;  // B*L = 3200

    // workspace (f32): At[10000] | c[100]  (40.4 KB)
    float* At = (float*)d_ws;
    float* c  = At + D_N * D_N;

    precomp_kernel<<<D_N, 128, 0, stream>>>(Wq, bq, Wk, emb, At, c);
    fused2_kernel<<<(G + 1) / 2, NTHR, 0, stream>>>(nbr, adj, emb, At, c,
                                                    Wv, bv, Ws, bs, d_out, G);
}